// Round 2
// baseline (258.484 us; speedup 1.0000x reference)
//
#include <hip/hip_runtime.h>
#include <hip/hip_bf16.h>
#include <stdint.h>

#define S_LEN 2048
#define D_EMB 1024
#define NHEAD 16
#define DHEAD 64
#define NBATCH 2
#define MROWS 4096  // NBATCH * S_LEN

typedef __attribute__((ext_vector_type(8))) short bf16x8;
typedef __attribute__((ext_vector_type(4))) float f32x4;
typedef unsigned short u16;
typedef unsigned int u32;

__device__ __forceinline__ u16 f2bf(float f) {
  union { float f; u32 u; } v; v.f = f;
  u32 r = v.u + 0x7fffu + ((v.u >> 16) & 1u);
  return (u16)(r >> 16);
}

__device__ __forceinline__ void gl_lds16(const void* g, void* l) {
  __builtin_amdgcn_global_load_lds(
      (const __attribute__((address_space(1))) u32*)g,
      (__attribute__((address_space(3))) u32*)l, 16, 0, 0);
}

// XOR swizzle for 128B-row tiles: spread 16B slot by row&7 (bijective involution)
__device__ __forceinline__ int swz(int o) { return o ^ (((o >> 7) & 7) << 4); }

__global__ void cast_f32_bf16(const float* __restrict__ in, u16* __restrict__ out, int n4) {
  int i = blockIdx.x * blockDim.x + threadIdx.x;
  if (i < n4) {
    float4 v = reinterpret_cast<const float4*>(in)[i];
    ushort4 o;
    o.x = f2bf(v.x); o.y = f2bf(v.y); o.z = f2bf(v.z); o.w = f2bf(v.w);
    reinterpret_cast<ushort4*>(out)[i] = o;
  }
}

// C = A[M,K] * B[N,K]^T + bias.  128x128 tile, 4 waves (2x2), BK=32.
// EPI 0: scatter to Q (pre-scaled 0.125) / K [B,H,S,dh] and V^T [B,H,dh,S] (bf16)
// EPI 1: fp32 store + bias
template <int EPI>
__launch_bounds__(256, 2)
__global__ void gemm_bt(const u16* __restrict__ A, const u16* __restrict__ Bm,
                        const float* __restrict__ bias, int M, int N, int K,
                        u16* __restrict__ q_out, u16* __restrict__ k_out,
                        u16* __restrict__ vt_out, float* __restrict__ f_out) {
  __shared__ __align__(16) u16 As[128 * 32];
  __shared__ __align__(16) u16 Bs[128 * 32];
  const int t = threadIdx.x;
  const int w = t >> 6, lane = t & 63;
  const int m0 = blockIdx.y * 128, n0 = blockIdx.x * 128;
  const int wr = w >> 1, wc = w & 1;

  f32x4 acc[4][4] = {};

  // staging: call c covers LDS bytes [c*4096 + w*1024 + lane*16, +16)
  const int e0 = w * 512 + lane * 8;          // elems, call 0
  const int ar0 = e0 >> 5, ac0 = e0 & 31;
  const int e1 = e0 + 2048;                   // call 1
  const int ar1 = e1 >> 5, ac1 = e1 & 31;
  const u16* Ab0 = A + (size_t)(m0 + ar0) * K + ac0;
  const u16* Ab1 = A + (size_t)(m0 + ar1) * K + ac1;
  const u16* Bb0 = Bm + (size_t)(n0 + ar0) * K + ac0;
  const u16* Bb1 = Bm + (size_t)(n0 + ar1) * K + ac1;
  u16* AsW = As + w * 512;  // wave-uniform dest; HW adds lane*16B
  u16* BsW = Bs + w * 512;

  const int lr = lane & 15, lg = lane >> 4;

  for (int kt = 0; kt < K; kt += 32) {
    __syncthreads();
    gl_lds16(Ab0 + kt, AsW);
    gl_lds16(Ab1 + kt, AsW + 2048);
    gl_lds16(Bb0 + kt, BsW);
    gl_lds16(Bb1 + kt, BsW + 2048);
    __syncthreads();
    bf16x8 af[4], bfr[4];
#pragma unroll
    for (int i = 0; i < 4; i++)
      af[i] = *(const bf16x8*)&As[(wr * 64 + i * 16 + lr) * 32 + lg * 8];
#pragma unroll
    for (int j = 0; j < 4; j++)
      bfr[j] = *(const bf16x8*)&Bs[(wc * 64 + j * 16 + lr) * 32 + lg * 8];
#pragma unroll
    for (int i = 0; i < 4; i++)
#pragma unroll
      for (int j = 0; j < 4; j++)
        acc[i][j] = __builtin_amdgcn_mfma_f32_16x16x32_bf16(af[i], bfr[j], acc[i][j], 0, 0, 0);
  }

#pragma unroll
  for (int j = 0; j < 4; j++) {
    const int n = n0 + wc * 64 + j * 16 + lr;
    const float bv = bias[n];
#pragma unroll
    for (int i = 0; i < 4; i++) {
#pragma unroll
      for (int r = 0; r < 4; r++) {
        const int m = m0 + wr * 64 + i * 16 + lg * 4 + r;
        float v = acc[i][j][r] + bv;
        if (EPI == 0) {
          const int which = n >> 10, nn = n & 1023;
          const int h = nn >> 6, d = nn & 63;
          const int b = m >> 11, s = m & 2047;
          if (which == 0)
            q_out[(size_t)(((b * NHEAD + h) * S_LEN) + s) * DHEAD + d] = f2bf(v * 0.125f);
          else if (which == 1)
            k_out[(size_t)(((b * NHEAD + h) * S_LEN) + s) * DHEAD + d] = f2bf(v);
          else
            vt_out[(size_t)(((b * NHEAD + h) * DHEAD) + d) * S_LEN + s] = f2bf(v);
        } else {
          f_out[(size_t)m * N + n] = v;
        }
      }
    }
  }
}

// Flash attention, causal. Block = (qt, bh): 64 q-rows, 4 waves x 16 rows.
// Q,K [B,H,S,64] bf16 (Q pre-scaled by 1/8); Vt [B,H,64,S] bf16.
// Out AO: [B*S, 1024] bf16 at col h*64+d.
__launch_bounds__(256, 2)
__global__ void attn_kernel(const u16* __restrict__ Qg, const u16* __restrict__ Kg,
                            const u16* __restrict__ Vtg, u16* __restrict__ AO,
                            const int* __restrict__ causal) {
  __shared__ __align__(16) u16 Kt[64 * 64];
  __shared__ __align__(16) u16 Vt[64 * 64];
  __shared__ __align__(16) u16 Pl[4][16 * 72];  // stride 72 elems (144B, 16B-aligned)

  const int t = threadIdx.x, w = t >> 6, lane = t & 63;
  const int lr = lane & 15, lg = lane >> 4;
  const int qt = blockIdx.x, bh = blockIdx.y;
  const size_t bh_off = (size_t)bh * S_LEN * DHEAD;
  const int cz = *causal;
  const int nk = cz ? (qt + 1) : (S_LEN / 64);

  // ---- stage Q tile (contiguous 8KB) into Kt with pre-swizzled source ----
  {
    const char* qb = (const char*)(Qg + bh_off + (size_t)qt * 64 * DHEAD);
#pragma unroll
    for (int c = 0; c < 2; c++) {
      int drel = c * 4096 + w * 1024 + lane * 16;
      gl_lds16(qb + swz(drel), (char*)Kt + c * 4096 + w * 1024);
    }
  }
  __syncthreads();
  bf16x8 qf[2];
#pragma unroll
  for (int ks = 0; ks < 2; ks++) {
    int r = w * 16 + lr;
    qf[ks] = *(const bf16x8*)((const char*)Kt + swz(r * 128 + ks * 64 + lg * 16));
  }

  float m_run[4], l_run[4];
  f32x4 o_acc[4] = {};
#pragma unroll
  for (int r = 0; r < 4; r++) { m_run[r] = -INFINITY; l_run[r] = 0.f; }

  for (int kt = 0; kt < nk; kt++) {
    __syncthreads();  // prior iter's frag reads done
    {
      const char* kb = (const char*)(Kg + bh_off + (size_t)kt * 64 * DHEAD);
#pragma unroll
      for (int c = 0; c < 2; c++) {
        int drel = c * 4096 + w * 1024 + lane * 16;
        gl_lds16(kb + swz(drel), (char*)Kt + c * 4096 + w * 1024);
      }
#pragma unroll
      for (int c = 0; c < 2; c++) {
        int drel = c * 4096 + w * 1024 + lane * 16;
        int o = swz(drel);
        int row = o >> 7, colb = o & 127;
        const char* vb = (const char*)Vtg +
                         (((size_t)bh * DHEAD + row) * S_LEN + (size_t)kt * 64) * 2 + colb;
        gl_lds16(vb, (char*)Vt + c * 4096 + w * 1024);
      }
    }
    __syncthreads();  // compiler drains vmcnt before barrier

    // ---- S = Q K^T (per wave: 16 q x 64 kv) ----
    f32x4 s[4] = {};
#pragma unroll
    for (int nf = 0; nf < 4; nf++) {
#pragma unroll
      for (int ks = 0; ks < 2; ks++) {
        int r = nf * 16 + lr;
        bf16x8 kf = *(const bf16x8*)((const char*)Kt + swz(r * 128 + ks * 64 + lg * 16));
        s[nf] = __builtin_amdgcn_mfma_f32_16x16x32_bf16(qf[ks], kf, s[nf], 0, 0, 0);
      }
    }

    if (cz && kt == qt) {
#pragma unroll
      for (int nf = 0; nf < 4; nf++)
#pragma unroll
        for (int r = 0; r < 4; r++) {
          int kv = nf * 16 + lr;
          int qr = w * 16 + lg * 4 + r;
          if (kv > qr) s[nf][r] = -INFINITY;
        }
    }

    // ---- online softmax: rows 4*lg+r, reduce across 16 lanes ----
    float rmax[4];
#pragma unroll
    for (int r = 0; r < 4; r++) {
      rmax[r] = s[0][r];
#pragma unroll
      for (int nf = 1; nf < 4; nf++) rmax[r] = fmaxf(rmax[r], s[nf][r]);
    }
#pragma unroll
    for (int mlt = 1; mlt < 16; mlt <<= 1)
#pragma unroll
      for (int r = 0; r < 4; r++) rmax[r] = fmaxf(rmax[r], __shfl_xor(rmax[r], mlt, 64));

    float scl[4];
#pragma unroll
    for (int r = 0; r < 4; r++) {
      float mn = fmaxf(m_run[r], rmax[r]);
      scl[r] = __expf(m_run[r] - mn);
      m_run[r] = mn;
    }

    float rsum[4] = {0.f, 0.f, 0.f, 0.f};
#pragma unroll
    for (int nf = 0; nf < 4; nf++)
#pragma unroll
      for (int r = 0; r < 4; r++) {
        float p = __expf(s[nf][r] - m_run[r]);
        rsum[r] += p;
        Pl[w][(lg * 4 + r) * 72 + nf * 16 + lr] = f2bf(p);
      }
#pragma unroll
    for (int mlt = 1; mlt < 16; mlt <<= 1)
#pragma unroll
      for (int r = 0; r < 4; r++) rsum[r] += __shfl_xor(rsum[r], mlt, 64);
#pragma unroll
    for (int r = 0; r < 4; r++) l_run[r] = l_run[r] * scl[r] + rsum[r];
#pragma unroll
    for (int nf = 0; nf < 4; nf++)
#pragma unroll
      for (int r = 0; r < 4; r++) o_acc[nf][r] *= scl[r];

    // intra-wave P write -> read fence
    asm volatile("s_waitcnt lgkmcnt(0)" ::: "memory");
    __builtin_amdgcn_sched_barrier(0);

    bf16x8 pf[2];
#pragma unroll
    for (int ks = 0; ks < 2; ks++)
      pf[ks] = *(const bf16x8*)&Pl[w][lr * 72 + ks * 32 + lg * 8];
#pragma unroll
    for (int nf = 0; nf < 4; nf++) {
#pragma unroll
      for (int ks = 0; ks < 2; ks++) {
        int r = nf * 16 + lr;
        bf16x8 vf = *(const bf16x8*)((const char*)Vt + swz(r * 128 + ks * 64 + lg * 16));
        o_acc[nf] = __builtin_amdgcn_mfma_f32_16x16x32_bf16(pf[ks], vf, o_acc[nf], 0, 0, 0);
      }
    }
  }

  // ---- epilogue: O / l -> AO[b*S+s][h*64+d] ----
  const int b = bh >> 4, h = bh & 15;
#pragma unroll
  for (int nf = 0; nf < 4; nf++)
#pragma unroll
    for (int r = 0; r < 4; r++) {
      float v = o_acc[nf][r] / l_run[r];
      int qrow = qt * 64 + w * 16 + lg * 4 + r;
      int d = nf * 16 + lr;
      AO[(size_t)(b * S_LEN + qrow) * D_EMB + h * DHEAD + d] = f2bf(v);
    }
}

extern "C" void kernel_launch(void* const* d_in, const int* in_sizes, int n_in,
                              void* d_out, int out_size, void* d_ws, size_t ws_size,
                              hipStream_t stream) {
  const float* x = (const float*)d_in[0];
  const float* w_in = (const float*)d_in[1];
  const float* b_in = (const float*)d_in[2];
  const float* w_out = (const float*)d_in[3];
  const float* b_out = (const float*)d_in[4];
  const int* causal = (const int*)d_in[5];
  float* out = (float*)d_out;

  char* p = (char*)d_ws;
  u16* xb = (u16*)p;  p += (size_t)MROWS * D_EMB * 2;
  u16* wib = (u16*)p; p += (size_t)3 * D_EMB * D_EMB * 2;
  u16* wob = (u16*)p; p += (size_t)D_EMB * D_EMB * 2;
  u16* Qg = (u16*)p;  p += (size_t)MROWS * D_EMB * 2;
  u16* Kg = (u16*)p;  p += (size_t)MROWS * D_EMB * 2;
  u16* Vtg = (u16*)p; p += (size_t)MROWS * D_EMB * 2;
  u16* AO = (u16*)p;  p += (size_t)MROWS * D_EMB * 2;

  {
    int n4 = MROWS * D_EMB / 4;
    cast_f32_bf16<<<(n4 + 255) / 256, 256, 0, stream>>>(x, xb, n4);
  }
  {
    int n4 = 3 * D_EMB * D_EMB / 4;
    cast_f32_bf16<<<(n4 + 255) / 256, 256, 0, stream>>>(w_in, wib, n4);
  }
  {
    int n4 = D_EMB * D_EMB / 4;
    cast_f32_bf16<<<(n4 + 255) / 256, 256, 0, stream>>>(w_out, wob, n4);
  }

  gemm_bt<0><<<dim3(3 * D_EMB / 128, MROWS / 128), 256, 0, stream>>>(
      xb, wib, b_in, MROWS, 3 * D_EMB, D_EMB, Qg, Kg, Vtg, nullptr);

  attn_kernel<<<dim3(S_LEN / 64, NBATCH * NHEAD), 256, 0, stream>>>(Qg, Kg, Vtg, AO, causal);

  gemm_bt<1><<<dim3(D_EMB / 128, MROWS / 128), 256, 0, stream>>>(
      AO, wob, b_out, MROWS, D_EMB, D_EMB, nullptr, nullptr, nullptr, out);
}

// Round 4
// 252.025 us; speedup vs baseline: 1.0256x; 1.0256x over previous
//
#include <hip/hip_runtime.h>
#include <hip/hip_bf16.h>
#include <stdint.h>

#define S_LEN 2048
#define D_EMB 1024
#define NHEAD 16
#define DHEAD 64
#define NBATCH 2
#define MROWS 4096  // NBATCH * S_LEN

typedef __attribute__((ext_vector_type(8))) short bf16x8;
typedef __attribute__((ext_vector_type(4))) float f32x4;
typedef unsigned short u16;
typedef unsigned int u32;

__device__ __forceinline__ u16 f2bf(float f) {
  union { float f; u32 u; } v; v.f = f;
  u32 r = v.u + 0x7fffu + ((v.u >> 16) & 1u);
  return (u16)(r >> 16);
}

__device__ __forceinline__ void gl_lds16(const void* g, void* l) {
  __builtin_amdgcn_global_load_lds(
      (const __attribute__((address_space(1))) u32*)g,
      (__attribute__((address_space(3))) u32*)l, 16, 0, 0);
}

// XOR swizzle for 128B-row tiles: spread 16B slot by row&7 (bijective involution)
__device__ __forceinline__ int swz(int o) { return o ^ (((o >> 7) & 7) << 4); }

__global__ void cast_f32_bf16(const float* __restrict__ in, u16* __restrict__ out, int n4) {
  int i = blockIdx.x * blockDim.x + threadIdx.x;
  if (i < n4) {
    float4 v = reinterpret_cast<const float4*>(in)[i];
    ushort4 o;
    o.x = f2bf(v.x); o.y = f2bf(v.y); o.z = f2bf(v.z); o.w = f2bf(v.w);
    reinterpret_cast<ushort4*>(out)[i] = o;
  }
}

// C = A[M,K] * B[N,K]^T + bias.  128x128 tile, 4 waves (2x2), BK=32, LDS dbuf.
// EPI 0: scatter to Q (pre-scaled 0.125) / K [B,H,S,dh] and V^T [B,H,dh,S] (bf16)
// EPI 1: fp32 store + bias
template <int EPI>
__launch_bounds__(256, 2)
__global__ void gemm_bt(const u16* __restrict__ A, const u16* __restrict__ Bm,
                        const float* __restrict__ bias, int M, int N, int K,
                        u16* __restrict__ q_out, u16* __restrict__ k_out,
                        u16* __restrict__ vt_out, float* __restrict__ f_out) {
  __shared__ __align__(16) u16 As[2][128 * 32];
  __shared__ __align__(16) u16 Bs[2][128 * 32];
  const int t = threadIdx.x;
  const int w = t >> 6, lane = t & 63;
  const int m0 = blockIdx.y * 128, n0 = blockIdx.x * 128;
  const int wr = w >> 1, wc = w & 1;

  f32x4 acc[4][4] = {};

  // staging: call c covers LDS bytes [c*4096 + w*1024 + lane*16, +16)
  const int e0 = w * 512 + lane * 8;          // elems, call 0
  const int ar0 = e0 >> 5, ac0 = e0 & 31;
  const int e1 = e0 + 2048;                   // call 1
  const int ar1 = e1 >> 5, ac1 = e1 & 31;
  const u16* Ab0 = A + (size_t)(m0 + ar0) * K + ac0;
  const u16* Ab1 = A + (size_t)(m0 + ar1) * K + ac1;
  const u16* Bb0 = Bm + (size_t)(n0 + ar0) * K + ac0;
  const u16* Bb1 = Bm + (size_t)(n0 + ar1) * K + ac1;

  const int lr = lane & 15, lg = lane >> 4;

#define GSTAGE(KT, BUF)                                \
  do {                                                 \
    gl_lds16(Ab0 + (KT), &As[BUF][w * 512]);           \
    gl_lds16(Ab1 + (KT), &As[BUF][w * 512 + 2048]);    \
    gl_lds16(Bb0 + (KT), &Bs[BUF][w * 512]);           \
    gl_lds16(Bb1 + (KT), &Bs[BUF][w * 512 + 2048]);    \
  } while (0)

  GSTAGE(0, 0);
  __syncthreads();
  int cur = 0;
  for (int kt = 0; kt < K; kt += 32) {
    if (kt + 32 < K) GSTAGE(kt + 32, cur ^ 1);  // loads fly during compute
    bf16x8 af[4], bfr[4];
#pragma unroll
    for (int i = 0; i < 4; i++)
      af[i] = *(const bf16x8*)&As[cur][(wr * 64 + i * 16 + lr) * 32 + lg * 8];
#pragma unroll
    for (int j = 0; j < 4; j++)
      bfr[j] = *(const bf16x8*)&Bs[cur][(wc * 64 + j * 16 + lr) * 32 + lg * 8];
#pragma unroll
    for (int i = 0; i < 4; i++)
#pragma unroll
      for (int j = 0; j < 4; j++)
        acc[i][j] = __builtin_amdgcn_mfma_f32_16x16x32_bf16(af[i], bfr[j], acc[i][j], 0, 0, 0);
    __syncthreads();  // drains vmcnt (next tile landed) + lgkm (our reads done)
    cur ^= 1;
  }
#undef GSTAGE

#pragma unroll
  for (int j = 0; j < 4; j++) {
    const int n = n0 + wc * 64 + j * 16 + lr;
    const float bv = bias[n];
#pragma unroll
    for (int i = 0; i < 4; i++) {
#pragma unroll
      for (int r = 0; r < 4; r++) {
        const int m = m0 + wr * 64 + i * 16 + lg * 4 + r;
        float v = acc[i][j][r] + bv;
        if (EPI == 0) {
          const int which = n >> 10, nn = n & 1023;
          const int h = nn >> 6, d = nn & 63;
          const int b = m >> 11, s = m & 2047;
          if (which == 0)
            q_out[(size_t)(((b * NHEAD + h) * S_LEN) + s) * DHEAD + d] = f2bf(v * 0.125f);
          else if (which == 1)
            k_out[(size_t)(((b * NHEAD + h) * S_LEN) + s) * DHEAD + d] = f2bf(v);
          else
            vt_out[(size_t)(((b * NHEAD + h) * DHEAD) + d) * S_LEN + s] = f2bf(v);
        } else {
          f_out[(size_t)m * N + n] = v;
        }
      }
    }
  }
}

// Flash attention, causal. Block = (qt, bh): 128 q-rows, 8 waves x 16 rows.
// K/V tiles (64 kv) double-buffered; stage(t+1) overlaps compute(t).
// Q,K [B,H,S,64] bf16 (Q pre-scaled by 1/8); Vt [B,H,64,S] bf16.
// Out AO: [B*S, 1024] bf16 at col h*64+d.
__launch_bounds__(512, 2)
__global__ void attn_kernel(const u16* __restrict__ Qg, const u16* __restrict__ Kg,
                            const u16* __restrict__ Vtg, u16* __restrict__ AO,
                            const int* __restrict__ causal) {
  __shared__ __align__(16) u16 Kt[2][64 * 64];
  __shared__ __align__(16) u16 Vt[2][64 * 64];
  __shared__ __align__(16) u16 Pl[8][16 * 72];  // stride 72 elems (144B, 16B-aligned)

  const int t = threadIdx.x, w = t >> 6, lane = t & 63;
  const int lr = lane & 15, lg = lane >> 4;
  const int qt = (int)(gridDim.x - 1) - (int)blockIdx.x;  // longest causal blocks first
  const int bh = blockIdx.y;
  const size_t bh_off = (size_t)bh * S_LEN * DHEAD;
  const int cz = *causal;
  const int q0 = qt * 128;
  const int nk = cz ? (2 * qt + 2) : (S_LEN / 64);

  // ---- stage Q tile (contiguous 16KB) into Kt[0..1] with pre-swizzled source ----
  {
    const char* qb = (const char*)(Qg + bh_off + (size_t)q0 * DHEAD);
#pragma unroll
    for (int c = 0; c < 2; c++) {
      int drel = c * 8192 + w * 1024 + lane * 16;
      gl_lds16(qb + swz(drel), (char*)&Kt[0][0] + c * 8192 + w * 1024);
    }
  }
  __syncthreads();
  bf16x8 qf[2];
#pragma unroll
  for (int ks = 0; ks < 2; ks++) {
    int rq = w * 16 + lr;
    qf[ks] = *(const bf16x8*)((const char*)&Kt[0][0] + swz(rq * 128 + ks * 64 + lg * 16));
  }
  __syncthreads();  // all waves hold qf before Kt[0] is overwritten

  // per-wave stagers: 8KB tile = 8 waves x 64 lanes x 16B, one call each
  auto stageK = [&](int kt, int buf) {
    const char* kb = (const char*)(Kg + bh_off + (size_t)kt * 64 * DHEAD);
    int drel = w * 1024 + lane * 16;
    gl_lds16(kb + swz(drel), (char*)&Kt[buf][0] + w * 1024);
  };
  auto stageV = [&](int kt, int buf) {
    int drel = w * 1024 + lane * 16;
    int o = swz(drel);
    int row = o >> 7, colb = o & 127;
    const char* vb = (const char*)Vtg +
                     (((size_t)bh * DHEAD + row) * S_LEN + (size_t)kt * 64) * 2 + colb;
    gl_lds16(vb, (char*)&Vt[buf][0] + w * 1024);
  };

  float m_run[4], l_run[4];
  f32x4 o_acc[4] = {};
#pragma unroll
  for (int r = 0; r < 4; r++) { m_run[r] = -INFINITY; l_run[r] = 0.f; }

  stageK(0, 0);
  stageV(0, 0);
  __syncthreads();
  int cur = 0;

  for (int kt = 0; kt < nk; kt++) {
    if (kt + 1 < nk) {  // prefetch next tile; lands during compute below
      stageK(kt + 1, cur ^ 1);
      stageV(kt + 1, cur ^ 1);
    }

    // ---- S = Q K^T (per wave: 16 q x 64 kv) ----
    f32x4 s[4] = {};
#pragma unroll
    for (int nf = 0; nf < 4; nf++) {
#pragma unroll
      for (int ks = 0; ks < 2; ks++) {
        int r = nf * 16 + lr;
        bf16x8 kf = *(const bf16x8*)((const char*)&Kt[cur][0] + swz(r * 128 + ks * 64 + lg * 16));
        s[nf] = __builtin_amdgcn_mfma_f32_16x16x32_bf16(qf[ks], kf, s[nf], 0, 0, 0);
      }
    }

    if (cz && (kt * 64 + 63 > q0 + w * 16)) {  // wave-uniform: diagonal tiles only
#pragma unroll
      for (int nf = 0; nf < 4; nf++)
#pragma unroll
        for (int r = 0; r < 4; r++) {
          int kv = kt * 64 + nf * 16 + lr;
          int qr = q0 + w * 16 + lg * 4 + r;
          if (kv > qr) s[nf][r] = -INFINITY;
        }
    }

    // ---- online softmax: rows 4*lg+r, reduce across 16 lanes ----
    float rmax[4];
#pragma unroll
    for (int r = 0; r < 4; r++) {
      rmax[r] = s[0][r];
#pragma unroll
      for (int nf = 1; nf < 4; nf++) rmax[r] = fmaxf(rmax[r], s[nf][r]);
    }
#pragma unroll
    for (int mlt = 1; mlt < 16; mlt <<= 1)
#pragma unroll
      for (int r = 0; r < 4; r++) rmax[r] = fmaxf(rmax[r], __shfl_xor(rmax[r], mlt, 64));

    float scl[4];
#pragma unroll
    for (int r = 0; r < 4; r++) {
      float mn = fmaxf(m_run[r], rmax[r]);
      scl[r] = __expf(m_run[r] - mn);
      m_run[r] = mn;
    }

    float rsum[4] = {0.f, 0.f, 0.f, 0.f};
#pragma unroll
    for (int nf = 0; nf < 4; nf++)
#pragma unroll
      for (int r = 0; r < 4; r++) {
        float p = __expf(s[nf][r] - m_run[r]);
        rsum[r] += p;
        Pl[w][(lg * 4 + r) * 72 + nf * 16 + lr] = f2bf(p);
      }
#pragma unroll
    for (int mlt = 1; mlt < 16; mlt <<= 1)
#pragma unroll
      for (int r = 0; r < 4; r++) rsum[r] += __shfl_xor(rsum[r], mlt, 64);
#pragma unroll
    for (int r = 0; r < 4; r++) l_run[r] = l_run[r] * scl[r] + rsum[r];
#pragma unroll
    for (int nf = 0; nf < 4; nf++)
#pragma unroll
      for (int r = 0; r < 4; r++) o_acc[nf][r] *= scl[r];

    // intra-wave P write -> read fence
    asm volatile("s_waitcnt lgkmcnt(0)" ::: "memory");
    __builtin_amdgcn_sched_barrier(0);

    bf16x8 pf[2];
#pragma unroll
    for (int ks = 0; ks < 2; ks++)
      pf[ks] = *(const bf16x8*)&Pl[w][lr * 72 + ks * 32 + lg * 8];
#pragma unroll
    for (int nf = 0; nf < 4; nf++) {
#pragma unroll
      for (int ks = 0; ks < 2; ks++) {
        int r = nf * 16 + lr;
        bf16x8 vf = *(const bf16x8*)((const char*)&Vt[cur][0] + swz(r * 128 + ks * 64 + lg * 16));
        o_acc[nf] = __builtin_amdgcn_mfma_f32_16x16x32_bf16(pf[ks], vf, o_acc[nf], 0, 0, 0);
      }
    }

    __syncthreads();  // drains vmcnt (tile t+1 landed) + lgkm (buf[cur] reads done)
    cur ^= 1;
  }

  // ---- epilogue: O / l -> AO[b*S+s][h*64+d] ----
  const int b = bh >> 4, h = bh & 15;
#pragma unroll
  for (int nf = 0; nf < 4; nf++)
#pragma unroll
    for (int r = 0; r < 4; r++) {
      float v = o_acc[nf][r] / l_run[r];
      int qrow = q0 + w * 16 + lg * 4 + r;
      int d = nf * 16 + lr;
      AO[(size_t)(b * S_LEN + qrow) * D_EMB + h * DHEAD + d] = f2bf(v);
    }
}

extern "C" void kernel_launch(void* const* d_in, const int* in_sizes, int n_in,
                              void* d_out, int out_size, void* d_ws, size_t ws_size,
                              hipStream_t stream) {
  const float* x = (const float*)d_in[0];
  const float* w_in = (const float*)d_in[1];
  const float* b_in = (const float*)d_in[2];
  const float* w_out = (const float*)d_in[3];
  const float* b_out = (const float*)d_in[4];
  const int* causal = (const int*)d_in[5];
  float* out = (float*)d_out;

  char* p = (char*)d_ws;
  u16* xb = (u16*)p;  p += (size_t)MROWS * D_EMB * 2;
  u16* wib = (u16*)p; p += (size_t)3 * D_EMB * D_EMB * 2;
  u16* wob = (u16*)p; p += (size_t)D_EMB * D_EMB * 2;
  u16* Qg = (u16*)p;  p += (size_t)MROWS * D_EMB * 2;
  u16* Kg = (u16*)p;  p += (size_t)MROWS * D_EMB * 2;
  u16* Vtg = (u16*)p; p += (size_t)MROWS * D_EMB * 2;
  u16* AO = (u16*)p;  p += (size_t)MROWS * D_EMB * 2;

  {
    int n4 = MROWS * D_EMB / 4;
    cast_f32_bf16<<<(n4 + 255) / 256, 256, 0, stream>>>(x, xb, n4);
  }
  {
    int n4 = 3 * D_EMB * D_EMB / 4;
    cast_f32_bf16<<<(n4 + 255) / 256, 256, 0, stream>>>(w_in, wib, n4);
  }
  {
    int n4 = D_EMB * D_EMB / 4;
    cast_f32_bf16<<<(n4 + 255) / 256, 256, 0, stream>>>(w_out, wob, n4);
  }

  gemm_bt<0><<<dim3(3 * D_EMB / 128, MROWS / 128), 256, 0, stream>>>(
      xb, wib, b_in, MROWS, 3 * D_EMB, D_EMB, Qg, Kg, Vtg, nullptr);

  attn_kernel<<<dim3(S_LEN / 128, NBATCH * NHEAD), 512, 0, stream>>>(Qg, Kg, Vtg, AO, causal);

  gemm_bt<1><<<dim3(D_EMB / 128, MROWS / 128), 256, 0, stream>>>(
      AO, wob, b_out, MROWS, D_EMB, D_EMB, nullptr, nullptr, nullptr, out);
}

// Round 5
// 206.586 us; speedup vs baseline: 1.2512x; 1.2200x over previous
//
#include <hip/hip_runtime.h>
#include <hip/hip_bf16.h>
#include <stdint.h>

#define S_LEN 2048
#define D_EMB 1024
#define NHEAD 16
#define DHEAD 64
#define NBATCH 2
#define MROWS 4096  // NBATCH * S_LEN

typedef __attribute__((ext_vector_type(8))) short bf16x8;
typedef __attribute__((ext_vector_type(4))) float f32x4;
typedef unsigned short u16;
typedef unsigned int u32;

__device__ __forceinline__ u16 f2bf(float f) {
  union { float f; u32 u; } v; v.f = f;
  u32 r = v.u + 0x7fffu + ((v.u >> 16) & 1u);
  return (u16)(r >> 16);
}

__device__ __forceinline__ void gl_lds16(const void* g, void* l) {
  __builtin_amdgcn_global_load_lds(
      (const __attribute__((address_space(1))) u32*)g,
      (__attribute__((address_space(3))) u32*)l, 16, 0, 0);
}

// XOR swizzle for 128B-row tiles: spread 16B slot by row&7 (bijective involution)
__device__ __forceinline__ int swz(int o) { return o ^ (((o >> 7) & 7) << 4); }

__global__ void cast_f32_bf16(const float* __restrict__ in, u16* __restrict__ out, int n4) {
  int i = blockIdx.x * blockDim.x + threadIdx.x;
  if (i < n4) {
    float4 v = reinterpret_cast<const float4*>(in)[i];
    ushort4 o;
    o.x = f2bf(v.x); o.y = f2bf(v.y); o.z = f2bf(v.z); o.w = f2bf(v.w);
    reinterpret_cast<ushort4*>(out)[i] = o;
  }
}

// C = A[M,K] * B[N,K]^T + bias.  128x128 tile, 4 waves (2x2), BK=32, LDS dbuf.
// EPI 0: scatter to Q (pre-scaled 0.125*log2e for exp2-domain softmax) /
//        K [B,H,S,dh] and V^T [B,H,dh,S] (bf16)
// EPI 1: fp32 store + bias
template <int EPI>
__launch_bounds__(256, 2)
__global__ void gemm_bt(const u16* __restrict__ A, const u16* __restrict__ Bm,
                        const float* __restrict__ bias, int M, int N, int K,
                        u16* __restrict__ q_out, u16* __restrict__ k_out,
                        u16* __restrict__ vt_out, float* __restrict__ f_out) {
  __shared__ __align__(16) u16 As[2][128 * 32];
  __shared__ __align__(16) u16 Bs[2][128 * 32];
  const int t = threadIdx.x;
  const int w = t >> 6, lane = t & 63;
  const int m0 = blockIdx.y * 128, n0 = blockIdx.x * 128;
  const int wr = w >> 1, wc = w & 1;

  f32x4 acc[4][4] = {};

  // staging: call c covers LDS bytes [c*4096 + w*1024 + lane*16, +16)
  const int e0 = w * 512 + lane * 8;          // elems, call 0
  const int ar0 = e0 >> 5, ac0 = e0 & 31;
  const int e1 = e0 + 2048;                   // call 1
  const int ar1 = e1 >> 5, ac1 = e1 & 31;
  const u16* Ab0 = A + (size_t)(m0 + ar0) * K + ac0;
  const u16* Ab1 = A + (size_t)(m0 + ar1) * K + ac1;
  const u16* Bb0 = Bm + (size_t)(n0 + ar0) * K + ac0;
  const u16* Bb1 = Bm + (size_t)(n0 + ar1) * K + ac1;

  const int lr = lane & 15, lg = lane >> 4;

#define GSTAGE(KT, BUF)                                \
  do {                                                 \
    gl_lds16(Ab0 + (KT), &As[BUF][w * 512]);           \
    gl_lds16(Ab1 + (KT), &As[BUF][w * 512 + 2048]);    \
    gl_lds16(Bb0 + (KT), &Bs[BUF][w * 512]);           \
    gl_lds16(Bb1 + (KT), &Bs[BUF][w * 512 + 2048]);    \
  } while (0)

  GSTAGE(0, 0);
  __syncthreads();
  int cur = 0;
  for (int kt = 0; kt < K; kt += 32) {
    if (kt + 32 < K) GSTAGE(kt + 32, cur ^ 1);  // loads fly during compute
    bf16x8 af[4], bfr[4];
#pragma unroll
    for (int i = 0; i < 4; i++)
      af[i] = *(const bf16x8*)&As[cur][(wr * 64 + i * 16 + lr) * 32 + lg * 8];
#pragma unroll
    for (int j = 0; j < 4; j++)
      bfr[j] = *(const bf16x8*)&Bs[cur][(wc * 64 + j * 16 + lr) * 32 + lg * 8];
#pragma unroll
    for (int i = 0; i < 4; i++)
#pragma unroll
      for (int j = 0; j < 4; j++)
        acc[i][j] = __builtin_amdgcn_mfma_f32_16x16x32_bf16(af[i], bfr[j], acc[i][j], 0, 0, 0);
    __syncthreads();  // drains vmcnt (next tile landed) + lgkm (our reads done)
    cur ^= 1;
  }
#undef GSTAGE

#pragma unroll
  for (int j = 0; j < 4; j++) {
    const int n = n0 + wc * 64 + j * 16 + lr;
    const float bv = bias[n];
#pragma unroll
    for (int i = 0; i < 4; i++) {
#pragma unroll
      for (int r = 0; r < 4; r++) {
        const int m = m0 + wr * 64 + i * 16 + lg * 4 + r;
        float v = acc[i][j][r] + bv;
        if (EPI == 0) {
          const int which = n >> 10, nn = n & 1023;
          const int h = nn >> 6, d = nn & 63;
          const int b = m >> 11, s = m & 2047;
          if (which == 0)  // 0.125 * log2(e): softmax runs in exp2 domain
            q_out[(size_t)(((b * NHEAD + h) * S_LEN) + s) * DHEAD + d] = f2bf(v * 0.180336880f);
          else if (which == 1)
            k_out[(size_t)(((b * NHEAD + h) * S_LEN) + s) * DHEAD + d] = f2bf(v);
          else
            vt_out[(size_t)(((b * NHEAD + h) * DHEAD) + d) * S_LEN + s] = f2bf(v);
        } else {
          f_out[(size_t)m * N + n] = v;
        }
      }
    }
  }
}

// Flash attention, causal. Block = (qt, bh): 128 q-rows, 8 waves x 16 rows.
// K/V tiles (64 kv) double-buffered; stage(t+1) overlaps compute(t).
// Q,K [B,H,S,64] bf16 (Q pre-scaled by 0.125*log2e); Vt [B,H,64,S] bf16.
// Softmax in exp2 domain; defer-max (THR=8) with lane-local fast gate;
// row-sums of P via all-ones MFMA (no shfl tree on the fast path).
// qt remap: co-resident blocks (b, b+256) get complementary qt -> balanced CUs.
// Out AO: [B*S, 1024] bf16 at col h*64+d.
__launch_bounds__(512, 2)
__global__ void attn_kernel(const u16* __restrict__ Qg, const u16* __restrict__ Kg,
                            const u16* __restrict__ Vtg, u16* __restrict__ AO,
                            const int* __restrict__ causal) {
  __shared__ __align__(16) u16 Kt[2][64 * 64];
  __shared__ __align__(16) u16 Vt[2][64 * 64];
  __shared__ __align__(16) u16 Pl[8][16 * 72];  // stride 72 elems (144B, 16B-aligned)

  const int t = threadIdx.x, w = t >> 6, lane = t & 63;
  const int lr = lane & 15, lg = lane >> 4;
  // balance: pair qt with (15-qt) on the same CU (co-resident classes mod 256)
  const int nqt = (int)gridDim.x;
  const int qt = ((int)blockIdx.y < 16) ? (nqt - 1 - (int)blockIdx.x) : (int)blockIdx.x;
  const int bh = blockIdx.y;
  const size_t bh_off = (size_t)bh * S_LEN * DHEAD;
  const int cz = *causal;
  const int q0 = qt * 128;
  const int nk = cz ? (2 * qt + 2) : (S_LEN / 64);

  bf16x8 ones;
#pragma unroll
  for (int e = 0; e < 8; e++) ones[e] = (short)16256;  // bf16 1.0

  // ---- stage Q tile (contiguous 16KB) into Kt[0..1] with pre-swizzled source ----
  {
    const char* qb = (const char*)(Qg + bh_off + (size_t)q0 * DHEAD);
#pragma unroll
    for (int c = 0; c < 2; c++) {
      int drel = c * 8192 + w * 1024 + lane * 16;
      gl_lds16(qb + swz(drel), (char*)&Kt[0][0] + c * 8192 + w * 1024);
    }
  }
  __syncthreads();
  bf16x8 qf[2];
#pragma unroll
  for (int ks = 0; ks < 2; ks++) {
    int rq = w * 16 + lr;
    qf[ks] = *(const bf16x8*)((const char*)&Kt[0][0] + swz(rq * 128 + ks * 64 + lg * 16));
  }
  __syncthreads();  // all waves hold qf before Kt[0] is overwritten

  // per-wave stagers: 8KB tile = 8 waves x 64 lanes x 16B, one call each
  auto stageK = [&](int kt, int buf) {
    const char* kb = (const char*)(Kg + bh_off + (size_t)kt * 64 * DHEAD);
    int drel = w * 1024 + lane * 16;
    gl_lds16(kb + swz(drel), (char*)&Kt[buf][0] + w * 1024);
  };
  auto stageV = [&](int kt, int buf) {
    int drel = w * 1024 + lane * 16;
    int o = swz(drel);
    int row = o >> 7, colb = o & 127;
    const char* vb = (const char*)Vtg +
                     (((size_t)bh * DHEAD + row) * S_LEN + (size_t)kt * 64) * 2 + colb;
    gl_lds16(vb, (char*)&Vt[buf][0] + w * 1024);
  };

  float m_run[4], l_run[4];
  f32x4 o_acc[4] = {};
#pragma unroll
  for (int r = 0; r < 4; r++) { m_run[r] = -INFINITY; l_run[r] = 0.f; }

  stageK(0, 0);
  stageV(0, 0);
  __syncthreads();
  int cur = 0;

  for (int kt = 0; kt < nk; kt++) {
    if (kt + 1 < nk) {  // prefetch next tile; lands during compute below
      stageK(kt + 1, cur ^ 1);
      stageV(kt + 1, cur ^ 1);
    }

    // ---- S = Q K^T (per wave: 16 q x 64 kv), exp2 domain ----
    f32x4 s[4] = {};
#pragma unroll
    for (int nf = 0; nf < 4; nf++) {
#pragma unroll
      for (int ks = 0; ks < 2; ks++) {
        int r = nf * 16 + lr;
        bf16x8 kf = *(const bf16x8*)((const char*)&Kt[cur][0] + swz(r * 128 + ks * 64 + lg * 16));
        s[nf] = __builtin_amdgcn_mfma_f32_16x16x32_bf16(qf[ks], kf, s[nf], 0, 0, 0);
      }
    }

    if (cz && (kt * 64 + 63 > q0 + w * 16)) {  // wave-uniform: diagonal tiles only
#pragma unroll
      for (int nf = 0; nf < 4; nf++)
#pragma unroll
        for (int r = 0; r < 4; r++) {
          int kv = kt * 64 + nf * 16 + lr;
          int qr = q0 + w * 16 + lg * 4 + r;
          if (kv > qr) s[nf][r] = -INFINITY;
        }
    }

    // ---- defer-max gate: lane-local maxima only (no cross-lane on fast path) ----
    float lmax[4];
#pragma unroll
    for (int r = 0; r < 4; r++)
      lmax[r] = fmaxf(fmaxf(s[0][r], s[1][r]), fmaxf(s[2][r], s[3][r]));
    float need = fmaxf(fmaxf(lmax[0] - m_run[0], lmax[1] - m_run[1]),
                       fmaxf(lmax[2] - m_run[2], lmax[3] - m_run[3]));
    if (!__all(need <= 8.0f)) {  // wave-uniform branch: exact row max + rescale
      float rmax[4];
#pragma unroll
      for (int r = 0; r < 4; r++) rmax[r] = lmax[r];
#pragma unroll
      for (int mlt = 1; mlt < 16; mlt <<= 1)
#pragma unroll
        for (int r = 0; r < 4; r++) rmax[r] = fmaxf(rmax[r], __shfl_xor(rmax[r], mlt, 64));
#pragma unroll
      for (int r = 0; r < 4; r++) {
        float mn = fmaxf(m_run[r], rmax[r]);
        float scl = exp2f(m_run[r] - mn);
        m_run[r] = mn;
        l_run[r] *= scl;
#pragma unroll
        for (int nf = 0; nf < 4; nf++) o_acc[nf][r] *= scl;
      }
    }

    // ---- P = exp2(S - m), bounded by 2^8 under defer ----
#pragma unroll
    for (int nf = 0; nf < 4; nf++)
#pragma unroll
      for (int r = 0; r < 4; r++) {
        float p = exp2f(s[nf][r] - m_run[r]);
        Pl[w][(lg * 4 + r) * 72 + nf * 16 + lr] = f2bf(p);
      }

    // intra-wave P write -> read fence
    asm volatile("s_waitcnt lgkmcnt(0)" ::: "memory");
    __builtin_amdgcn_sched_barrier(0);

    bf16x8 pf[2];
#pragma unroll
    for (int ks = 0; ks < 2; ks++)
      pf[ks] = *(const bf16x8*)&Pl[w][lr * 72 + ks * 32 + lg * 8];

    // row sums of P via ones-MFMA: lane gets sum for rows lg*4+r (all cols equal)
    f32x4 lsum = {};
    lsum = __builtin_amdgcn_mfma_f32_16x16x32_bf16(pf[0], ones, lsum, 0, 0, 0);
    lsum = __builtin_amdgcn_mfma_f32_16x16x32_bf16(pf[1], ones, lsum, 0, 0, 0);

#pragma unroll
    for (int nf = 0; nf < 4; nf++) {
#pragma unroll
      for (int ks = 0; ks < 2; ks++) {
        int r = nf * 16 + lr;
        bf16x8 vf = *(const bf16x8*)((const char*)&Vt[cur][0] + swz(r * 128 + ks * 64 + lg * 16));
        o_acc[nf] = __builtin_amdgcn_mfma_f32_16x16x32_bf16(pf[ks], vf, o_acc[nf], 0, 0, 0);
      }
    }
#pragma unroll
    for (int r = 0; r < 4; r++) l_run[r] += lsum[r];

    __syncthreads();  // drains vmcnt (tile t+1 landed) + lgkm (buf[cur] reads done)
    cur ^= 1;
  }

  // ---- epilogue: O / l -> AO[b*S+s][h*64+d] ----
  const int b = bh >> 4, h = bh & 15;
#pragma unroll
  for (int nf = 0; nf < 4; nf++)
#pragma unroll
    for (int r = 0; r < 4; r++) {
      float v = o_acc[nf][r] / l_run[r];
      int qrow = q0 + w * 16 + lg * 4 + r;
      int d = nf * 16 + lr;
      AO[(size_t)(b * S_LEN + qrow) * D_EMB + h * DHEAD + d] = f2bf(v);
    }
}

extern "C" void kernel_launch(void* const* d_in, const int* in_sizes, int n_in,
                              void* d_out, int out_size, void* d_ws, size_t ws_size,
                              hipStream_t stream) {
  const float* x = (const float*)d_in[0];
  const float* w_in = (const float*)d_in[1];
  const float* b_in = (const float*)d_in[2];
  const float* w_out = (const float*)d_in[3];
  const float* b_out = (const float*)d_in[4];
  const int* causal = (const int*)d_in[5];
  float* out = (float*)d_out;

  char* p = (char*)d_ws;
  u16* xb = (u16*)p;  p += (size_t)MROWS * D_EMB * 2;
  u16* wib = (u16*)p; p += (size_t)3 * D_EMB * D_EMB * 2;
  u16* wob = (u16*)p; p += (size_t)D_EMB * D_EMB * 2;
  u16* Qg = (u16*)p;  p += (size_t)MROWS * D_EMB * 2;
  u16* Kg = (u16*)p;  p += (size_t)MROWS * D_EMB * 2;
  u16* Vtg = (u16*)p; p += (size_t)MROWS * D_EMB * 2;
  u16* AO = (u16*)p;  p += (size_t)MROWS * D_EMB * 2;

  {
    int n4 = MROWS * D_EMB / 4;
    cast_f32_bf16<<<(n4 + 255) / 256, 256, 0, stream>>>(x, xb, n4);
  }
  {
    int n4 = 3 * D_EMB * D_EMB / 4;
    cast_f32_bf16<<<(n4 + 255) / 256, 256, 0, stream>>>(w_in, wib, n4);
  }
  {
    int n4 = D_EMB * D_EMB / 4;
    cast_f32_bf16<<<(n4 + 255) / 256, 256, 0, stream>>>(w_out, wob, n4);
  }

  gemm_bt<0><<<dim3(3 * D_EMB / 128, MROWS / 128), 256, 0, stream>>>(
      xb, wib, b_in, MROWS, 3 * D_EMB, D_EMB, Qg, Kg, Vtg, nullptr);

  attn_kernel<<<dim3(S_LEN / 128, NBATCH * NHEAD), 512, 0, stream>>>(Qg, Kg, Vtg, AO, causal);

  gemm_bt<1><<<dim3(D_EMB / 128, MROWS / 128), 256, 0, stream>>>(
      AO, wob, b_out, MROWS, D_EMB, D_EMB, nullptr, nullptr, nullptr, out);
}